// Round 4
// baseline (258.236 us; speedup 1.0000x reference)
//
#include <hip/hip_runtime.h>
#include <hip/hip_bf16.h>
#include <stdint.h>

typedef unsigned short ushort_t;
typedef __attribute__((ext_vector_type(8))) short short8;
typedef __attribute__((ext_vector_type(4))) float floatx4;

// ---------- helpers ----------
__device__ __forceinline__ ushort_t f2bf(float f) {
    union { float f; unsigned u; } v; v.f = f;
    unsigned r = v.u + 0x7fffu + ((v.u >> 16) & 1u);   // RTNE
    return (ushort_t)(r >> 16);
}

__device__ __forceinline__ short8 pack8(float4 a, float4 b) {
    short8 r;
    r[0] = (short)f2bf(a.x); r[1] = (short)f2bf(a.y);
    r[2] = (short)f2bf(a.z); r[3] = (short)f2bf(a.w);
    r[4] = (short)f2bf(b.x); r[5] = (short)f2bf(b.y);
    r[6] = (short)f2bf(b.z); r[7] = (short)f2bf(b.w);
    return r;
}

__device__ __forceinline__ void async16(ushort_t* lds, const ushort_t* g) {
    __builtin_amdgcn_global_load_lds(
        (const __attribute__((address_space(1))) unsigned int*)g,
        (__attribute__((address_space(3))) unsigned int*)lds, 16, 0, 0);
}

// ================= the reshape trap (load-bearing comment) =================
// Reference: w3 axes (i0,i1,o0,o1), flat = ii*4096+oo (ii=i0*32+i1, oo=o0*64+o1),
// then reshape(4096,1024): W_mat[r][c] with r*1024+c = ii*4096+oo, i.e.
//   ii = r>>2 ,  oo = (r&3)*1024 + c      (c is x's column!)
// out[s][r] = sum_c x[s][c]*W_mat[r][c]
//           = sum_k A2[r>>2][k] * Z[s][(r&3)*256+k],
//   Z[s][b*256+k] = sum_c x[s][c]*B2[k][b*1024+c]
// where A2[ii][k]=sum_r1 c0*c1 (k=r0*16+r2), B2[k][oo]=sum_r3 c2*c3.
// ===========================================================================

// ---------- prep: V[k'][c] (B-operand of gemm_z) and A2b[a][k], both bf16 ----------
// blocks [0,4096): V (1024x1024);  [4096,5120): A2b (1024x256)
__global__ __launch_bounds__(256) void prep(const float* __restrict__ c0,
                                            const float* __restrict__ c1,
                                            const float* __restrict__ c2,
                                            const float* __restrict__ c3,
                                            ushort_t* __restrict__ V,
                                            ushort_t* __restrict__ A2b) {
    const int blk = blockIdx.x, t = threadIdx.x;
    if (blk < 4096) {
        int id = blk * 256 + t;            // [0, 1024*1024)
        int c = id & 1023, kp = id >> 10;  // kp = b*256+k
        int b = kp >> 8, k = kp & 255;
        int r0 = k >> 4, r2 = k & 15;
        int o0 = b * 16 + (c >> 6), o1 = c & 63;   // oo = b*1024+c
        const float* p2 = c2 + (r2 * 64 + o0) * 16;   // stride 1 over r3
        const float* p3 = c3 + o1 * 16 + r0;          // stride 1024 over r3
        float s = 0.f;
#pragma unroll
        for (int r3 = 0; r3 < 16; r3++) s += p2[r3] * p3[r3 * 1024];
        V[id] = f2bf(s);                   // V[kp*1024 + c], c-coalesced
    } else {
        int id = (blk - 4096) * 256 + t;   // [0, 1024*256)
        int k = id & 255, a = id >> 8;
        int r0 = k >> 4, r2 = k & 15;
        int i0 = a >> 5, i1 = a & 31;
        const float* p0 = c0 + (r0 * 32 + i0) * 16;   // stride 1 over r1
        const float* p1 = c1 + i1 * 16 + r2;          // stride 512 over r1
        float s = 0.f;
#pragma unroll
        for (int r1 = 0; r1 < 16; r1++) s += p0[r1] * p1[r1 * 512];
        A2b[id] = f2bf(s);                 // A2b[a*256 + k], k-coalesced
    }
}

// ---------- gemm_z: Z[8192][1024] = cvt_bf16(x) @ V^T ; fp32 A cvt inline ----------
// m97 structure, 128x128 tile, BK=32, grid (64,8). B via async16; A via VGPR+cvt.
__global__ __launch_bounds__(256) void gemm_z(const float* __restrict__ x,
                                              const ushort_t* __restrict__ V,
                                              ushort_t* __restrict__ Z) {
    __shared__ ushort_t As[128 * 32];
    __shared__ ushort_t Bs[128 * 32];
    const int t = threadIdx.x;
    const int row0 = blockIdx.x * 128;  // s
    const int col0 = blockIdx.y * 128;  // k'
    const int w = t >> 6, l = t & 63;
    const int wm = w >> 1, wn = w & 1;
    const int quad = l >> 4, ln = l & 15;

    floatx4 acc[4][4] = {};

    const float*    aSrc = x + (size_t)(row0 + (t >> 2)) * 1024 + (t & 3) * 8;
    const ushort_t* bSrc = V + (size_t)(col0 + (t >> 2)) * 1024 + (t & 3) * 8;

    for (int kk = 0; kk < 1024; kk += 32) {
        async16(&Bs[t * 8],        bSrc + kk);
        async16(&Bs[2048 + t * 8], bSrc + 64 * 1024 + kk);
        float4 f0 = *(const float4*)(aSrc + kk);
        float4 f1 = *(const float4*)(aSrc + kk + 4);
        float4 f2 = *(const float4*)(aSrc + 64 * 1024 + kk);
        float4 f3 = *(const float4*)(aSrc + 64 * 1024 + kk + 4);
        *(short8*)&As[t * 8]        = pack8(f0, f1);
        *(short8*)&As[2048 + t * 8] = pack8(f2, f3);
        __syncthreads();

        short8 a[4], b[4];
#pragma unroll
        for (int ti = 0; ti < 4; ti++)
            a[ti] = *(const short8*)&As[(wm * 64 + ti * 16 + ln) * 32 + quad * 8];
#pragma unroll
        for (int tj = 0; tj < 4; tj++)
            b[tj] = *(const short8*)&Bs[(wn * 64 + tj * 16 + ln) * 32 + quad * 8];
#pragma unroll
        for (int ti = 0; ti < 4; ti++)
#pragma unroll
            for (int tj = 0; tj < 4; tj++)
                acc[ti][tj] = __builtin_amdgcn_mfma_f32_16x16x32_bf16(
                    a[ti], b[tj], acc[ti][tj], 0, 0, 0);
        __syncthreads();
    }

    // D layout: col=lane&15, row=quad*4+reg  [m89]; Z bf16, ld=1024
#pragma unroll
    for (int tj = 0; tj < 4; tj++) {
        const int n = col0 + wn * 64 + tj * 16 + ln;
#pragma unroll
        for (int ti = 0; ti < 4; ti++) {
            const int m = row0 + wm * 64 + ti * 16 + quad * 4;
#pragma unroll
            for (int r = 0; r < 4; r++)
                Z[(size_t)(m + r) * 1024 + n] = f2bf(acc[ti][tj][r]);
        }
    }
}

// ---------- gemm_out: out[s][j] = sum_k A2[j>>2][k]*Z[s][(j&3)*256+k] + bias[j] ----------
// Block: 128 s x 128 j (32 a x 4 b). A2-slice LDS-resident (padded ld=264).
// b unrolled outer -> acc[ti][b] compile-time indexed. Epilogue: float4 over b.
__global__ __launch_bounds__(256) void gemm_out(const ushort_t* __restrict__ Z,
                                                const ushort_t* __restrict__ A2b,
                                                const float* __restrict__ bias,
                                                float* __restrict__ out) {
    __shared__ ushort_t Zs[2 * 128 * 32];   // two 32-wide k-chunks, m97 layout
    __shared__ ushort_t A2s[32 * 264];      // +8 pad: row stride 132 dw = 4 mod 32 -> 2-way (free)
    const int t = threadIdx.x;
    const int row0 = blockIdx.x * 128;      // s
    const int col0 = blockIdx.y * 128;      // j
    const int a0 = col0 >> 2;               // 32 a-values per block
    const int w = t >> 6, l = t & 63;
    const int wm = w >> 1, wn = w & 1;
    const int quad = l >> 4, ln = l & 15;

    floatx4 acc[4][4] = {};   // [ti(s)][b]

    // stage A2 slice (32 x 256) once, VGPR path so padding is allowed
#pragma unroll
    for (int q = 0; q < 4; q++) {
        int g = q * 2048 + t * 8;           // flat element in the 32x256 block
        int r = g >> 8, cidx = g & 255;
        short8 v = *(const short8*)(A2b + (size_t)(a0 + r) * 256 + cidx);
        *(short8*)&A2s[r * 264 + cidx] = v;
    }

    const ushort_t* zSrc = Z + (size_t)(row0 + (t >> 2)) * 1024 + (t & 3) * 8;

#pragma unroll
    for (int b = 0; b < 4; b++) {
        for (int kk = 0; kk < 256; kk += 64) {
            const ushort_t* src = zSrc + b * 256 + kk;
            async16(&Zs[t * 8],        src);
            async16(&Zs[2048 + t * 8], src + 64 * 1024);
            async16(&Zs[4096 + t * 8], src + 32);
            async16(&Zs[6144 + t * 8], src + 64 * 1024 + 32);
            __syncthreads();   // also covers pre-loop A2s writes on first pass
#pragma unroll
            for (int half = 0; half < 2; half++) {
                short8 bb = *(const short8*)&A2s[(wn * 16 + ln) * 264 + kk + half * 32 + quad * 8];
#pragma unroll
                for (int ti = 0; ti < 4; ti++) {
                    short8 av = *(const short8*)&Zs[half * 4096 + (wm * 64 + ti * 16 + ln) * 32 + quad * 8];
                    acc[ti][b] = __builtin_amdgcn_mfma_f32_16x16x32_bf16(
                        av, bb, acc[ti][b], 0, 0, 0);
                }
            }
            __syncthreads();
        }
    }

    // epilogue: C/D col=lane&15 -> a-offset, row=quad*4+reg -> s. j = aIdx*4 + b.
    const int aIdx = a0 + wn * 16 + ln;
    const float4 bv = *(const float4*)(bias + aIdx * 4);
#pragma unroll
    for (int ti = 0; ti < 4; ti++) {
#pragma unroll
        for (int r = 0; r < 4; r++) {
            const int s = row0 + wm * 64 + ti * 16 + quad * 4 + r;
            float4 o;
            o.x = acc[ti][0][r] + bv.x;
            o.y = acc[ti][1][r] + bv.y;
            o.z = acc[ti][2][r] + bv.z;
            o.w = acc[ti][3][r] + bv.w;
            *(float4*)(out + (size_t)s * 4096 + aIdx * 4) = o;
        }
    }
}

extern "C" void kernel_launch(void* const* d_in, const int* in_sizes, int n_in,
                              void* d_out, int out_size, void* d_ws, size_t ws_size,
                              hipStream_t stream) {
    const float* x    = (const float*)d_in[0];   // 8192*1024
    const float* c0   = (const float*)d_in[1];   // 16*32*16
    const float* c1   = (const float*)d_in[2];   // 16*32*16
    const float* c2   = (const float*)d_in[3];   // 16*64*16
    const float* c3   = (const float*)d_in[4];   // 16*64*16
    const float* bias = (const float*)d_in[5];   // 4096
    float* out = (float*)d_out;                  // 8192*4096

    char* ws = (char*)d_ws;
    ushort_t* V   = (ushort_t*)ws;                    // 2 MB   bf16 V[k'][c]
    ushort_t* A2b = (ushort_t*)(ws + (2u << 20));     // 0.5 MB bf16 A2b[a][k]
    ushort_t* Zb  = (ushort_t*)(ws + (4u << 20));     // 16 MB  bf16 Z[s][k']

    hipLaunchKernelGGL(prep, dim3(5120), dim3(256), 0, stream, c0, c1, c2, c3, V, A2b);
    hipLaunchKernelGGL(gemm_z, dim3(64, 8), dim3(256), 0, stream, x, V, Zb);
    hipLaunchKernelGGL(gemm_out, dim3(64, 32), dim3(256), 0, stream, Zb, A2b, bias, out);
}